// Round 5
// baseline (945.473 us; speedup 1.0000x reference)
//
#include <hip/hip_runtime.h>
#include <hip/hip_cooperative_groups.h>
#include <hip/hip_bf16.h>
#include <stdint.h>

// Problem constants
#define BQ 128    // batch
#define NJ 512    // input capsules j
#define DD 300    // input dim
#define NC 10     // num_capsule i
#define DC 64     // dim_capsule k
#define MM 640    // NC*DC
#define KP 320    // K padded (mult of 64)

namespace cg = cooperative_groups;

typedef __attribute__((ext_vector_type(8))) short short8;
typedef __attribute__((ext_vector_type(4))) float f32x4;

__device__ __forceinline__ float bf2f(ushort u) { return __uint_as_float((uint)u << 16); }
__device__ __forceinline__ ushort f2bf(float f) {
    __hip_bfloat16 h = __float2bfloat16(f);
    return *(ushort*)&h;
}

// ================= phase bodies (shared by mega kernel and discrete fallback) =================

// cast x[row][d] f32 -> xb[row][KP] bf16 (zero-padded d>=300). g = row*40 + cg2.
__device__ __forceinline__ void cast_x_body(int g, const float* __restrict__ x,
                                            ushort* __restrict__ xb) {
    int row = g / 40, cg2 = g - row * 40;
    const float* src = x + (size_t)row * DD + cg2 * 8;
    float4 a = make_float4(0.f, 0.f, 0.f, 0.f), b4 = a;
    if (cg2 < 37) { a = *(const float4*)src; b4 = *(const float4*)(src + 4); }
    else if (cg2 == 37) { a = *(const float4*)src; }
    union { ushort u[8]; uint4 v; } o;
    float f[8] = {a.x, a.y, a.z, a.w, b4.x, b4.y, b4.z, b4.w};
#pragma unroll
    for (int e = 0; e < 8; ++e) o.u[e] = f2bf(f[e]);
    *(uint4*)(xb + (size_t)row * KP + cg2 * 8) = o.v;
}

// wt[m][k] = bf16(W[k][m]), k zero-padded to KP
__device__ __forceinline__ void cast_w_body(int idx, const float* __restrict__ W,
                                            ushort* __restrict__ wt) {
    int m = idx / KP, k = idx - m * KP;
    float v = (k < DD) ? W[(size_t)k * MM + m] : 0.f;
    wt[idx] = f2bf(v);
}

// transpose xb -> xt (d-major), fused column-sum sx[b][d] += sum_j x[b,j,d].
// unit = (b, jt 0..7, dt 0..4): 64j x 64d tile; needs 256 threads + smem >= 9728B.
__device__ __forceinline__ void xt_body(int unit, const ushort* __restrict__ xb,
                                        ushort* __restrict__ xt, float* __restrict__ sx,
                                        char* smem) {
    ushort (*lt)[76] = (ushort(*)[76])smem;      // pitch 76 u16 (152B, b64-aligned)
    int b = unit / 40, rem = unit - b * 40, jt = rem / 5, dt = rem - (rem / 5) * 5;
    int t = threadIdx.x;
    int r = t >> 2, c = t & 3;
#pragma unroll
    for (int h = 0; h < 2; ++h) {
        uint4 v = *(const uint4*)(xb +
            (size_t)(b * 512 + jt * 64 + r) * KP + dt * 64 + (c + 4 * h) * 8);
        *(uint2*)&lt[r][(c + 4 * h) * 8]     = make_uint2(v.x, v.y);
        *(uint2*)&lt[r][(c + 4 * h) * 8 + 4] = make_uint2(v.z, v.w);
    }
    __syncthreads();
    int dr = t >> 2;
    float s = 0.f;
#pragma unroll
    for (int h = 0; h < 2; ++h) {
        int jc = c + 4 * h;
        union { ushort u[8]; uint4 v; } o;
#pragma unroll
        for (int e = 0; e < 8; ++e) o.u[e] = lt[jc * 8 + e][dr];
        *(uint4*)(xt + (size_t)(b * KP + dt * 64 + dr) * 512 + jt * 64 + jc * 8) = o.v;
#pragma unroll
        for (int e = 0; e < 8; ++e) s += bf2f(o.u[e]);
    }
    s += __shfl_xor(s, 1, 64);
    s += __shfl_xor(s, 2, 64);
    if (c == 0) atomicAdd(&sx[b * KP + dt * 64 + dr], s);
    __syncthreads();                              // lt reusable by next unit
}

// routing pass unit (b, jb): bl-MFMA (K=320) -> softmax over i -> Cx-MFMA (K=64).
// 256 threads; smem >= 16*68*4 = 4352B.
__device__ __forceinline__ void pass_body(int unit, const ushort* __restrict__ xb,
                                          const ushort* __restrict__ xt,
                                          const ushort* __restrict__ wot,
                                          float* __restrict__ pcx, char* smem) {
    float (*c_lds)[68] = (float(*)[68])smem;     // [16][68] pitch 272B

    const int t = threadIdx.x, w = t >> 6, lane = t & 63;
    const int quad = lane >> 4, r = lane & 15;
    const int b = unit >> 3, jb = unit & 7;
    const int j0 = jb * 64 + w * 16;

    // phase 1: bl GEMM, D[i'(16) x j(16)] per wave, K = 320 (Wo as hi+lo bf16)
    f32x4 acc = {0.f, 0.f, 0.f, 0.f};
    const ushort* aph = wot + ((size_t)(b * 2 + 0) * 16 + r) * KP + quad * 8;
    const ushort* apl = aph + 16 * KP;
    const ushort* bp  = xb + (size_t)(b * 512 + j0 + r) * KP + quad * 8;
#pragma unroll
    for (int ks = 0; ks < 10; ++ks) {
        short8 bf = *(const short8*)(bp  + ks * 32);
        short8 ah = *(const short8*)(aph + ks * 32);
        short8 al = *(const short8*)(apl + ks * 32);
        acc = __builtin_amdgcn_mfma_f32_16x16x32_bf16(ah, bf, acc, 0, 0, 0);
        acc = __builtin_amdgcn_mfma_f32_16x16x32_bf16(al, bf, acc, 0, 0, 0);
    }
    // lane (quad,r): bl[i' = quad*4+p][j = j0+r]; rows 10..15 garbage (masked below)

    // phase 2: softmax over i' (valid i' < 10)
    float mx;
    if (quad < 2)       mx = fmaxf(fmaxf(acc[0], acc[1]), fmaxf(acc[2], acc[3]));
    else if (quad == 2) mx = fmaxf(acc[0], acc[1]);
    else                mx = -1e30f;
    mx = fmaxf(mx, __shfl_xor(mx, 16, 64));
    mx = fmaxf(mx, __shfl_xor(mx, 32, 64));
    float e0 = (quad < 3) ? __expf(acc[0] - mx) : 0.f;
    float e1 = (quad < 3) ? __expf(acc[1] - mx) : 0.f;
    float e2 = (quad < 2) ? __expf(acc[2] - mx) : 0.f;
    float e3 = (quad < 2) ? __expf(acc[3] - mx) : 0.f;
    float ss = e0 + e1 + e2 + e3;
    ss += __shfl_xor(ss, 16, 64);
    ss += __shfl_xor(ss, 32, 64);
    float inv = 1.f / ss;
    int col = w * 16 + r;
    if (quad < 2) {
        c_lds[quad * 4 + 0][col] = e0 * inv;
        c_lds[quad * 4 + 1][col] = e1 * inv;
        c_lds[quad * 4 + 2][col] = e2 * inv;
        c_lds[quad * 4 + 3][col] = e3 * inv;
    } else if (quad == 2) {
        c_lds[8][col] = e0 * inv;
        c_lds[9][col] = e1 * inv;
    }
    __syncthreads();

    // phase 3: Cx GEMM, D[i''(16) x d(16)] x 5 N-tiles/wave, K = 64 (this jb)
    short8 a2h[2], a2l[2];
#pragma unroll
    for (int ks = 0; ks < 2; ++ks) {
        const float* cp = &c_lds[r][ks * 32 + quad * 8];
        union { ushort u[8]; short8 v; } H, L;
#pragma unroll
        for (int e = 0; e < 8; ++e) {
            float cf = cp[e];
            ushort hu = f2bf(cf);
            float hf = bf2f(hu);
            H.u[e] = hu;
            L.u[e] = f2bf(cf - hf);
        }
        a2h[ks] = H.v; a2l[ks] = L.v;
    }
    f32x4 cacc[5] = {};
#pragma unroll
    for (int nt = 0; nt < 5; ++nt) {
        const ushort* bb = xt +
            (size_t)(b * KP + (w * 5 + nt) * 16 + r) * 512 + jb * 64 + quad * 8;
        short8 b20 = *(const short8*)(bb);
        short8 b21 = *(const short8*)(bb + 32);
        cacc[nt] = __builtin_amdgcn_mfma_f32_16x16x32_bf16(a2h[0], b20, cacc[nt], 0, 0, 0);
        cacc[nt] = __builtin_amdgcn_mfma_f32_16x16x32_bf16(a2l[0], b20, cacc[nt], 0, 0, 0);
        cacc[nt] = __builtin_amdgcn_mfma_f32_16x16x32_bf16(a2h[1], b21, cacc[nt], 0, 0, 0);
        cacc[nt] = __builtin_amdgcn_mfma_f32_16x16x32_bf16(a2l[1], b21, cacc[nt], 0, 0, 0);
    }
    float* pout = pcx + (size_t)(b * 8 + jb) * 10 * KP;
#pragma unroll
    for (int nt = 0; nt < 5; ++nt) {
        int d = (w * 5 + nt) * 16 + r;
        if (quad < 2) {
#pragma unroll
            for (int p = 0; p < 4; ++p) pout[(quad * 4 + p) * KP + d] = cacc[nt][p];
        } else if (quad == 2) {
            pout[8 * KP + d] = cacc[nt][0];
            pout[9 * KP + d] = cacc[nt][1];
        }
    }
    __syncthreads();                              // c_lds reusable by next unit
}

// combine unit (b, i): reduce jb partials -> po -> squash -> out; Wo = W^T.out.
// mode 0: src = sx (cx = 0.1*sx). mode 1: mid. mode 2: last (write dst, skip Wo).
// 256 threads; smem >= (320+256+64)*4 = 2560B.
__device__ __forceinline__ void out_body(int unit, int mode, const float* __restrict__ src,
                                         const float* __restrict__ W,
                                         const ushort* __restrict__ wt,
                                         ushort* __restrict__ wot,
                                         float* __restrict__ dst, char* smem) {
    float* cx   = (float*)smem;                  // [320]
    float* red  = cx + KP;                       // [256]
    float* outl = red + 256;                     // [64]
    const int b = unit / 10, i = unit - b * 10;
    const int t = threadIdx.x, w = t >> 6, lane = t & 63;

    // phase 1: cx[d] for this (b,i)
    for (int d = t; d < KP; d += 256) {
        float v;
        if (mode == 0) {
            v = 0.1f * src[(size_t)b * KP + d];
        } else {
            const float* pp = src + (size_t)b * 8 * 10 * KP + (size_t)i * KP + d;
            v = 0.f;
#pragma unroll
            for (int jb = 0; jb < 8; ++jb) v += pp[(size_t)jb * 10 * KP];
        }
        cx[d] = v;
    }
    __syncthreads();

    // phase 2: po[k] = sum_d cx[d]*wt[i*64+k][d]; d split over 4 waves (80 each)
    {
        const ushort* wr = wt + (size_t)(i * 64 + lane) * KP + w * 80;
        const float* cr = cx + w * 80;
        float pp = 0.f;
#pragma unroll
        for (int kk = 0; kk < 10; ++kk) {
            union { uint4 q; ushort u[8]; } wv;
            wv.q = *(const uint4*)(wr + kk * 8);
#pragma unroll
            for (int e = 0; e < 8; ++e) pp += bf2f(wv.u[e]) * cr[kk * 8 + e];
        }
        red[w * 64 + lane] = pp;
    }
    __syncthreads();
    if (w == 0) {
        float po = red[lane] + red[64 + lane] + red[128 + lane] + red[192 + lane];
        float sq = po * po;
#pragma unroll
        for (int m = 32; m >= 1; m >>= 1) sq += __shfl_xor(sq, m, 64);
        float ov = po * rsqrtf(sq + 1e-7f);
        if (mode == 2) dst[(size_t)b * MM + i * 64 + lane] = ov;
        else           outl[lane] = ov;
    }
    if (mode != 2) {
        __syncthreads();
        // phase 3: Wo[d] = sum_k W[d][i*64+k]*outl[k]; hi/lo bf16 split
        for (int d = t; d < KP; d += 256) {
            float s = 0.f;
            if (d < DD) {
                const float4* wr4 = (const float4*)(W + (size_t)d * MM + i * 64);
                const float4* ol4 = (const float4*)outl;
#pragma unroll
                for (int kk = 0; kk < 16; ++kk) {
                    float4 a = wr4[kk];
                    float4 o = ol4[kk];
                    s += a.x * o.x + a.y * o.y + a.z * o.z + a.w * o.w;
                }
            }
            ushort hu = f2bf(s);
            wot[((size_t)(b * 2 + 0) * 16 + i) * KP + d] = hu;
            wot[((size_t)(b * 2 + 1) * 16 + i) * KP + d] = f2bf(s - bf2f(hu));
        }
    }
    __syncthreads();                              // cx/red/outl reusable by next unit
}

// ================= persistent cooperative mega-kernel =================
// All phases grid-stride; LDS persists per block; 10 grid syncs replace 12 kernel
// boundaries. Bodies identical to the discrete (round-4-verified) kernels.

__global__ __launch_bounds__(256, 4)
void k_mega(const float* __restrict__ x, const float* __restrict__ W,
            ushort* __restrict__ xb, ushort* __restrict__ xt,
            ushort* __restrict__ wt, ushort* __restrict__ wot,
            float* __restrict__ pcx, float* __restrict__ sx,
            float* __restrict__ out) {
    __shared__ __align__(16) char smem[9760];
    cg::grid_group gg = cg::this_grid();
    const int t = threadIdx.x, B0 = blockIdx.x, G = gridDim.x;

    for (int g = B0 * 256 + t; g < BQ * NJ * 40; g += G * 256) cast_x_body(g, x, xb);
    for (int g = B0 * 256 + t; g < MM * KP;      g += G * 256) cast_w_body(g, W, wt);
    for (int g = B0 * 256 + t; g < BQ * KP;      g += G * 256) sx[g] = 0.f;
    gg.sync();
    for (int u = B0; u < BQ * 40; u += G) xt_body(u, xb, xt, sx, smem);
    gg.sync();
    for (int u = B0; u < BQ * NC; u += G) out_body(u, 0, sx, W, wt, wot, out, smem);
    for (int it = 1; it <= 4; ++it) {
        gg.sync();
        for (int u = B0; u < BQ * 8; u += G) pass_body(u, xb, xt, wot, pcx, smem);
        gg.sync();
        for (int u = B0; u < BQ * NC; u += G)
            out_body(u, (it == 4) ? 2 : 1, pcx, W, wt, wot, out, smem);
    }
}

// ================= discrete fallback kernels (round-4 path) =================

__global__ __launch_bounds__(256) void k_cast_x(const float* __restrict__ x,
                                                ushort* __restrict__ xb) {
    cast_x_body(blockIdx.x * 256 + threadIdx.x, x, xb);
}
__global__ __launch_bounds__(256) void k_cast_w(const float* __restrict__ W,
                                                ushort* __restrict__ wt) {
    cast_w_body(blockIdx.x * 256 + threadIdx.x, W, wt);
}
__global__ __launch_bounds__(256) void k_zero(float4* __restrict__ p) {
    p[blockIdx.x * 256 + threadIdx.x] = make_float4(0.f, 0.f, 0.f, 0.f);
}
__global__ __launch_bounds__(256) void k_xt(const ushort* __restrict__ xb,
                                            ushort* __restrict__ xt,
                                            float* __restrict__ sx) {
    __shared__ __align__(16) char smem[9760];
    xt_body(blockIdx.x, xb, xt, sx, smem);
}
__global__ __launch_bounds__(256) void k_pass(const ushort* __restrict__ xb,
                                              const ushort* __restrict__ xt,
                                              const ushort* __restrict__ wot,
                                              float* __restrict__ pcx) {
    __shared__ __align__(16) char smem[4384];
    pass_body(blockIdx.x, xb, xt, wot, pcx, smem);
}
__global__ __launch_bounds__(256) void k_out(int mode, const float* __restrict__ src,
                                             const float* __restrict__ W,
                                             const ushort* __restrict__ wt,
                                             ushort* __restrict__ wot,
                                             float* __restrict__ dst) {
    __shared__ __align__(16) char smem[2592];
    out_body(blockIdx.x, mode, src, W, wt, wot, dst, smem);
}

// ================= launch =================

extern "C" void kernel_launch(void* const* d_in, const int* in_sizes, int n_in,
                              void* d_out, int out_size, void* d_ws, size_t ws_size,
                              hipStream_t stream) {
    const float* x = (const float*)d_in[0];   // [128,512,300]
    const float* W = (const float*)d_in[1];   // [1,300,640]
    float* out = (float*)d_out;               // [128,10,64]

    char* ws = (char*)d_ws;
    size_t o = 0;
    ushort* xb  = (ushort*)(ws + o); o += (size_t)BQ * NJ * KP * 2;        // 41.9 MB
    ushort* xt  = (ushort*)(ws + o); o += (size_t)BQ * KP * NJ * 2;        // 41.9 MB
    ushort* wt  = (ushort*)(ws + o); o += (size_t)MM * KP * 2;             // 0.4 MB
    ushort* wot = (ushort*)(ws + o); o += (size_t)BQ * 2 * 16 * KP * 2;    // 2.6 MB
    float* pcx  = (float*)(ws + o);  o += (size_t)BQ * 8 * 10 * KP * 4;    // 13.1 MB
    float* sx   = (float*)(ws + o);  o += (size_t)BQ * KP * 4;             // 0.16 MB

    // cooperative grid size: occupancy-query once, cached (gfx950: 256 CUs)
    static int coop_grid = -2;                // -2 untried, -1 disabled
    if (coop_grid == -2) {
        int nb = 0;
        if (hipOccupancyMaxActiveBlocksPerMultiprocessor(
                &nb, (const void*)k_mega, 256, 0) == hipSuccess && nb > 0) {
            coop_grid = nb * 256;
            if (coop_grid > 2048) coop_grid = 2048;
        } else {
            coop_grid = -1;
        }
    }

    bool done = false;
    if (coop_grid > 0) {
        void* kargs[] = {(void*)&x, (void*)&W, (void*)&xb, (void*)&xt, (void*)&wt,
                         (void*)&wot, (void*)&pcx, (void*)&sx, (void*)&out};
        hipError_t e = hipLaunchCooperativeKernel((const void*)k_mega,
                                                  dim3(coop_grid), dim3(256),
                                                  kargs, 0, stream);
        if (e == hipSuccess) done = true;
        else coop_grid = -1;                  // don't retry on later calls
    }

    if (!done) {                              // discrete round-4 path
        k_cast_x<<<(BQ * NJ * 40) / 256, 256, 0, stream>>>(x, xb);
        k_cast_w<<<(MM * KP) / 256, 256, 0, stream>>>(W, wt);
        k_zero<<<(BQ * KP) / (4 * 256), 256, 0, stream>>>((float4*)sx);
        k_xt<<<BQ * 40, 256, 0, stream>>>(xb, xt, sx);
        k_out<<<BQ * NC, 256, 0, stream>>>(0, sx, W, wt, wot, nullptr);
        for (int it = 1; it <= 4; ++it) {
            k_pass<<<BQ * 8, 256, 0, stream>>>(xb, xt, wot, pcx);
            k_out<<<BQ * NC, 256, 0, stream>>>((it == 4) ? 2 : 1, pcx, W, wt, wot,
                                               (it == 4) ? out : nullptr);
        }
    }
}

// Round 6
// 462.326 us; speedup vs baseline: 2.0450x; 2.0450x over previous
//
#include <hip/hip_runtime.h>
#include <hip/hip_bf16.h>
#include <stdint.h>

// Problem constants
#define BQ 128    // batch
#define NJ 512    // input capsules j
#define DD 300    // input dim
#define NC 10     // num_capsule i
#define DC 64     // dim_capsule k
#define MM 640    // NC*DC
#define KP 320    // K padded (mult of 64)

typedef __attribute__((ext_vector_type(8))) short short8;
typedef __attribute__((ext_vector_type(4))) float f32x4;

__device__ __forceinline__ float bf2f(ushort u) { return __uint_as_float((uint)u << 16); }
__device__ __forceinline__ ushort f2bf(float f) {
    __hip_bfloat16 h = __float2bfloat16(f);
    return *(ushort*)&h;
}

// ---------------- cast x f32 -> xb bf16 [row][KP] ----------------

__global__ __launch_bounds__(256)
void k_cast_x(const float* __restrict__ x, ushort* __restrict__ xb) {
    int g = blockIdx.x * 256 + threadIdx.x;      // 65536 rows * 40 groups
    int row = g / 40, cg2 = g - row * 40;
    const float* src = x + (size_t)row * DD + cg2 * 8;
    float4 a = make_float4(0.f, 0.f, 0.f, 0.f), b4 = a;
    if (cg2 < 37) { a = *(const float4*)src; b4 = *(const float4*)(src + 4); }
    else if (cg2 == 37) { a = *(const float4*)src; }
    union { ushort u[8]; uint4 v; } o;
    float f[8] = {a.x, a.y, a.z, a.w, b4.x, b4.y, b4.z, b4.w};
#pragma unroll
    for (int e = 0; e < 8; ++e) o.u[e] = f2bf(f[e]);
    *(uint4*)(xb + (size_t)row * KP + cg2 * 8) = o.v;
}

// ---------------- prep: wt[m][k] = bf16(W[k][m]) + zero sx ----------------

__global__ __launch_bounds__(256)
void k_prep(const float* __restrict__ W, ushort* __restrict__ wt,
            float* __restrict__ sx) {
    int idx = blockIdx.x * 256 + threadIdx.x;    // grid 800 -> 204800
    int m = idx / KP, k = idx - m * KP;
    float v = (k < DD) ? W[(size_t)k * MM + m] : 0.f;
    wt[idx] = f2bf(v);
    if (idx < BQ * KP) sx[idx] = 0.f;
}

// ---------------- transpose xb -> xt (d-major), fused column-sum sx ----------------

__global__ __launch_bounds__(256)
void k_xt(const ushort* __restrict__ xb, ushort* __restrict__ xt,
          float* __restrict__ sx) {
    __shared__ ushort lt[64][76];                 // pitch 152B (b64-aligned)
    int blk = blockIdx.x;
    int b = blk / 40, rem = blk - b * 40, jt = rem / 5, dt = rem - (rem / 5) * 5;
    int t = threadIdx.x;
    int r = t >> 2, c = t & 3;
#pragma unroll
    for (int h = 0; h < 2; ++h) {
        uint4 v = *(const uint4*)(xb +
            (size_t)(b * 512 + jt * 64 + r) * KP + dt * 64 + (c + 4 * h) * 8);
        *(uint2*)&lt[r][(c + 4 * h) * 8]     = make_uint2(v.x, v.y);
        *(uint2*)&lt[r][(c + 4 * h) * 8 + 4] = make_uint2(v.z, v.w);
    }
    __syncthreads();
    int dr = t >> 2;
    float s = 0.f;
#pragma unroll
    for (int h = 0; h < 2; ++h) {
        int jc = c + 4 * h;
        union { ushort u[8]; uint4 v; } o;
#pragma unroll
        for (int e = 0; e < 8; ++e) o.u[e] = lt[jc * 8 + e][dr];
        *(uint4*)(xt + (size_t)(b * KP + dt * 64 + dr) * 512 + jt * 64 + jc * 8) = o.v;
#pragma unroll
        for (int e = 0; e < 8; ++e) s += bf2f(o.u[e]);
    }
    s += __shfl_xor(s, 1, 64);
    s += __shfl_xor(s, 2, 64);
    if (c == 0) atomicAdd(&sx[b * KP + dt * 64 + dr], s);
}

// ---------------- k_route: ALL 5 routing iterations for one b, in one block ----------------
// 128 blocks x 1024 thr (16 waves). Couplings (softmax over i, sum_j, squash, Wo)
// are per-b => block-local; only __syncthreads between phases (grid.sync measured
// ~100us/sync in R5 — never again). Wo, c, Cx, out all live in LDS; only xb/xt
// stream from L2/L3. Phase math verbatim from the round-4-verified bodies.

__global__ __launch_bounds__(1024)
void k_route(const ushort* __restrict__ xb, const ushort* __restrict__ xt,
             const ushort* __restrict__ wt, const float* __restrict__ W,
             const float* __restrict__ sx, float* __restrict__ out) {
    __shared__ __align__(16) ushort c_h[16][520];   // c hi, [i][j] pitch 1040B
    __shared__ __align__(16) ushort c_l[16][520];   // c lo
    __shared__ __align__(16) ushort wo_h[16][328];  // Wo hi, [i][d] pitch 656B
    __shared__ __align__(16) ushort wo_l[16][328];  // Wo lo
    __shared__ __align__(16) float  cxl[NC][KP + 8];// Cx, [i][d]
    __shared__ __align__(16) float  outl[MM];       // squash(out)

    const int b = blockIdx.x;
    const int t = threadIdx.x;
    const int w = t >> 6, lane = t & 63;
    const int quad = lane >> 4, r = lane & 15;

    // prologue: cxl = 0.1 * sx (uniform c at iteration 0)
    for (int u = t; u < NC * KP; u += 1024) {
        int i = u / KP, d = u - i * KP;
        cxl[i][d] = 0.1f * sx[(size_t)b * KP + d];
    }
    __syncthreads();

    for (int it = 0; ; ++it) {
        // ---- po + squash: threads 0..639, wave w == i, lane == k
        if (t < MM) {
            const int i = w;
            const ushort* wr = wt + (size_t)t * KP;
            float po = 0.f;
#pragma unroll 5
            for (int kk = 0; kk < 40; ++kk) {
                union { uint4 q; ushort u[8]; } wv;
                wv.q = *(const uint4*)(wr + kk * 8);
                const float* cr = &cxl[i][kk * 8];
#pragma unroll
                for (int e = 0; e < 8; ++e) po += bf2f(wv.u[e]) * cr[e];
            }
            float sq = po * po;
#pragma unroll
            for (int m = 32; m >= 1; m >>= 1) sq += __shfl_xor(sq, m, 64);
            float ov = po * rsqrtf(sq + 1e-7f);
            if (it == 4) out[(size_t)b * MM + t] = ov;
            else         outl[t] = ov;
        }
        if (it == 4) return;
        __syncthreads();                         // outl ready

        // ---- Wo[i][d] = sum_k W[d][i*64+k] * outl[i*64+k]; hi/lo bf16 into LDS
        for (int u = t; u < NC * KP; u += 1024) {
            int i = u / KP, d = u - i * KP;
            float s = 0.f;
            if (d < DD) {
                const float4* wr4 = (const float4*)(W + (size_t)d * MM + i * 64);
                const float4* ol4 = (const float4*)(&outl[i * 64]);
#pragma unroll 4
                for (int kk = 0; kk < 16; ++kk) {
                    float4 a = wr4[kk];
                    float4 o = ol4[kk];
                    s += a.x * o.x + a.y * o.y + a.z * o.z + a.w * o.w;
                }
            }
            ushort hu = f2bf(s);
            wo_h[i][d] = hu;
            wo_l[i][d] = f2bf(s - bf2f(hu));
        }
        __syncthreads();                         // wo ready (rows 10-15 garbage: masked)

        // ---- bl GEMM + softmax + c store: 32 j-tiles of 16, 2 per wave
#pragma unroll
        for (int h = 0; h < 2; ++h) {
            int jt = w + 16 * h;
            f32x4 acc = {0.f, 0.f, 0.f, 0.f}, ac2 = {0.f, 0.f, 0.f, 0.f};
            const ushort* bp = xb + (size_t)(b * NJ + jt * 16 + r) * KP + quad * 8;
#pragma unroll
            for (int ks = 0; ks < 10; ++ks) {
                short8 bf = *(const short8*)(bp + ks * 32);
                short8 ah = *(const short8*)(&wo_h[r][ks * 32 + quad * 8]);
                short8 al = *(const short8*)(&wo_l[r][ks * 32 + quad * 8]);
                acc = __builtin_amdgcn_mfma_f32_16x16x32_bf16(ah, bf, acc, 0, 0, 0);
                ac2 = __builtin_amdgcn_mfma_f32_16x16x32_bf16(al, bf, ac2, 0, 0, 0);
            }
            float blv[4];
#pragma unroll
            for (int p = 0; p < 4; ++p) blv[p] = acc[p] + ac2[p];
            // softmax over i' = quad*4+p (valid < 10), per column j = jt*16+r
            float mx;
            if (quad < 2)       mx = fmaxf(fmaxf(blv[0], blv[1]), fmaxf(blv[2], blv[3]));
            else if (quad == 2) mx = fmaxf(blv[0], blv[1]);
            else                mx = -1e30f;
            mx = fmaxf(mx, __shfl_xor(mx, 16, 64));
            mx = fmaxf(mx, __shfl_xor(mx, 32, 64));
            float e0 = (quad < 3) ? __expf(blv[0] - mx) : 0.f;
            float e1 = (quad < 3) ? __expf(blv[1] - mx) : 0.f;
            float e2 = (quad < 2) ? __expf(blv[2] - mx) : 0.f;
            float e3 = (quad < 2) ? __expf(blv[3] - mx) : 0.f;
            float ss = e0 + e1 + e2 + e3;
            ss += __shfl_xor(ss, 16, 64);
            ss += __shfl_xor(ss, 32, 64);
            float inv = 1.f / ss;
            int j = jt * 16 + r;
            if (quad < 2) {
                float cc[4] = {e0 * inv, e1 * inv, e2 * inv, e3 * inv};
#pragma unroll
                for (int p = 0; p < 4; ++p) {
                    ushort hu = f2bf(cc[p]);
                    c_h[quad * 4 + p][j] = hu;
                    c_l[quad * 4 + p][j] = f2bf(cc[p] - bf2f(hu));
                }
            } else if (quad == 2) {
                float c8 = e0 * inv, c9 = e1 * inv;
                ushort h8 = f2bf(c8), h9 = f2bf(c9);
                c_h[8][j] = h8; c_l[8][j] = f2bf(c8 - bf2f(h8));
                c_h[9][j] = h9; c_l[9][j] = f2bf(c9 - bf2f(h9));
            }
        }
        __syncthreads();                         // c ready (rows 10-15 garbage: masked)

        // ---- Cx GEMM: D[i(16) x d(16)], 20 d-tiles over 16 waves, K = 512
#pragma unroll
        for (int h = 0; h < 2; ++h) {
            int dt = w + 16 * h;
            if (dt < 20) {
                f32x4 ca = {0.f, 0.f, 0.f, 0.f}, c2 = {0.f, 0.f, 0.f, 0.f};
                const ushort* bb = xt + (size_t)(b * KP + dt * 16 + r) * 512 + quad * 8;
#pragma unroll
                for (int kw = 0; kw < 16; ++kw) {
                    short8 bf = *(const short8*)(bb + kw * 32);
                    short8 ah = *(const short8*)(&c_h[r][kw * 32 + quad * 8]);
                    short8 al = *(const short8*)(&c_l[r][kw * 32 + quad * 8]);
                    ca = __builtin_amdgcn_mfma_f32_16x16x32_bf16(ah, bf, ca, 0, 0, 0);
                    c2 = __builtin_amdgcn_mfma_f32_16x16x32_bf16(al, bf, c2, 0, 0, 0);
                }
                int d = dt * 16 + r;
                if (quad < 2) {
#pragma unroll
                    for (int p = 0; p < 4; ++p) cxl[quad * 4 + p][d] = ca[p] + c2[p];
                } else if (quad == 2) {
                    cxl[8][d] = ca[0] + c2[0];
                    cxl[9][d] = ca[1] + c2[1];
                }
            }
        }
        __syncthreads();                         // cxl ready for next po
    }
}

// ---------------- launch: 4 dispatches, no grid-wide sync ----------------

extern "C" void kernel_launch(void* const* d_in, const int* in_sizes, int n_in,
                              void* d_out, int out_size, void* d_ws, size_t ws_size,
                              hipStream_t stream) {
    const float* x = (const float*)d_in[0];   // [128,512,300]
    const float* W = (const float*)d_in[1];   // [1,300,640]
    float* out = (float*)d_out;               // [128,10,64]

    char* ws = (char*)d_ws;
    size_t o = 0;
    ushort* xb = (ushort*)(ws + o); o += (size_t)BQ * NJ * KP * 2;   // 41.9 MB
    ushort* xt = (ushort*)(ws + o); o += (size_t)BQ * KP * NJ * 2;   // 41.9 MB
    ushort* wt = (ushort*)(ws + o); o += (size_t)MM * KP * 2;        // 0.4 MB
    float*  sx = (float*)(ws + o);  o += (size_t)BQ * KP * 4;        // 0.16 MB

    k_cast_x<<<(BQ * NJ * 40) / 256, 256, 0, stream>>>(x, xb);
    k_prep<<<(MM * KP) / 256, 256, 0, stream>>>(W, wt, sx);
    k_xt<<<BQ * 40, 256, 0, stream>>>(xb, xt, sx);
    k_route<<<BQ, 1024, 0, stream>>>(xb, xt, wt, W, sx, out);
}

// Round 7
// 382.046 us; speedup vs baseline: 2.4748x; 1.2101x over previous
//
#include <hip/hip_runtime.h>
#include <hip/hip_bf16.h>
#include <stdint.h>

// Problem constants
#define BQ 128    // batch
#define NJ 512    // input capsules j
#define DD 300    // input dim
#define NC 10     // num_capsule i
#define DC 64     // dim_capsule k
#define MM 640    // NC*DC
#define KP 320    // K padded (mult of 64)

typedef __attribute__((ext_vector_type(8))) short short8;
typedef __attribute__((ext_vector_type(4))) float f32x4;

__device__ __forceinline__ float bf2f(ushort u) { return __uint_as_float((uint)u << 16); }
__device__ __forceinline__ ushort f2bf(float f) {
    __hip_bfloat16 h = __float2bfloat16(f);
    return *(ushort*)&h;
}

// ---------------- cast x f32 -> xb bf16 [row][KP] ----------------

__global__ __launch_bounds__(256)
void k_cast_x(const float* __restrict__ x, ushort* __restrict__ xb) {
    int g = blockIdx.x * 256 + threadIdx.x;      // 65536 rows * 40 groups
    int row = g / 40, cg2 = g - row * 40;
    const float* src = x + (size_t)row * DD + cg2 * 8;
    float4 a = make_float4(0.f, 0.f, 0.f, 0.f), b4 = a;
    if (cg2 < 37) { a = *(const float4*)src; b4 = *(const float4*)(src + 4); }
    else if (cg2 == 37) { a = *(const float4*)src; }
    union { ushort u[8]; uint4 v; } o;
    float f[8] = {a.x, a.y, a.z, a.w, b4.x, b4.y, b4.z, b4.w};
#pragma unroll
    for (int e = 0; e < 8; ++e) o.u[e] = f2bf(f[e]);
    *(uint4*)(xb + (size_t)row * KP + cg2 * 8) = o.v;
}

// ---------------- cast W -> wt[m][k] bf16 (k-major, zero-padded) ----------------

__global__ __launch_bounds__(256)
void k_cast_w(const float* __restrict__ W, ushort* __restrict__ wt) {
    int idx = blockIdx.x * 256 + threadIdx.x;    // 204800
    int m = idx / KP, k = idx - m * KP;
    float v = (k < DD) ? W[(size_t)k * MM + m] : 0.f;
    wt[idx] = f2bf(v);
}

// ---------------- routing pass: ONE xb sweep per iteration ----------------
// Round-6 lesson: every 84 MB sweep costs ~43us (~2 TB/s wall, structure-
// independent) -> minimize bytes swept. This kernel stages the 64j x 320d xb
// tile in LDS ONCE and consumes it both ways: d-major rows feed the bl-MFMA
// (round-4-verified operand convention), j-major columns feed a VALU
// outer-product for Cx (c stays f32 -> better numerics than hi/lo MFMA).
// xt and k_xt are gone; per-iter traffic halves (84 -> 42 MB).
// Grid = (b, jo 0..7) = 1024 blocks, 320 threads (5 waves).
// FIRST=1: iteration 0, c uniform = 0.1 (softmax of zero logits).

#define XP 344   // LDS row pitch in u16: 688B = 172 dw; 12r mod 32 -> 2-way max

template<int FIRST>
__global__ __launch_bounds__(320)
void k_pass(const ushort* __restrict__ xb, const ushort* __restrict__ wot,
            float* __restrict__ pcx) {
    __shared__ __align__(16) ushort xs[64 * XP];    // 44032 B
    __shared__ __align__(16) float c_lds[10][68];   // 2720 B, f32 c

    const int t = threadIdx.x, w = t >> 6, lane = t & 63;
    const int quad = lane >> 4, r = lane & 15;
    const int blk = blockIdx.x, b = blk >> 3, jo = blk & 7;

    // ---- stage xb tile [64 j][320 d] -> LDS (coalesced uint4, 8 per thread)
    {
        const uint4* gsrc = (const uint4*)(xb + (size_t)(b * NJ + jo * 64) * KP);
        int idx = t;
#pragma unroll
        for (int s = 0; s < 8; ++s, idx += 320) {
            int row = idx / 40, col = idx - row * 40;
            *(uint4*)(xs + row * XP + col * 8) = gsrc[row * 40 + col];
        }
    }
    __syncthreads();

    if (!FIRST && w < 4) {
        // ---- bl GEMM: D[i'(16) x j(16)] per wave, K=320, Wo as hi+lo bf16
        f32x4 acc = {0.f, 0.f, 0.f, 0.f}, ac2 = {0.f, 0.f, 0.f, 0.f};
        const ushort* aph = wot + ((size_t)(b * 2 + 0) * 16 + r) * KP + quad * 8;
        const ushort* apl = aph + 16 * KP;
        const ushort* bp  = xs + (w * 16 + r) * XP + quad * 8;
#pragma unroll
        for (int ks = 0; ks < 10; ++ks) {
            short8 bf = *(const short8*)(bp + ks * 32);
            short8 ah = *(const short8*)(aph + ks * 32);
            short8 al = *(const short8*)(apl + ks * 32);
            acc = __builtin_amdgcn_mfma_f32_16x16x32_bf16(ah, bf, acc, 0, 0, 0);
            ac2 = __builtin_amdgcn_mfma_f32_16x16x32_bf16(al, bf, ac2, 0, 0, 0);
        }
        float blv[4];
#pragma unroll
        for (int p = 0; p < 4; ++p) blv[p] = acc[p] + ac2[p];

        // ---- softmax over i' = quad*4+p (valid < 10), per column j
        float mx;
        if (quad < 2)       mx = fmaxf(fmaxf(blv[0], blv[1]), fmaxf(blv[2], blv[3]));
        else if (quad == 2) mx = fmaxf(blv[0], blv[1]);
        else                mx = -1e30f;
        mx = fmaxf(mx, __shfl_xor(mx, 16, 64));
        mx = fmaxf(mx, __shfl_xor(mx, 32, 64));
        float e0 = (quad < 3) ? __expf(blv[0] - mx) : 0.f;
        float e1 = (quad < 3) ? __expf(blv[1] - mx) : 0.f;
        float e2 = (quad < 2) ? __expf(blv[2] - mx) : 0.f;
        float e3 = (quad < 2) ? __expf(blv[3] - mx) : 0.f;
        float ss = e0 + e1 + e2 + e3;
        ss += __shfl_xor(ss, 16, 64);
        ss += __shfl_xor(ss, 32, 64);
        float inv = 1.f / ss;
        int j = w * 16 + r;
        if (quad < 2) {
            c_lds[quad * 4 + 0][j] = e0 * inv;
            c_lds[quad * 4 + 1][j] = e1 * inv;
            c_lds[quad * 4 + 2][j] = e2 * inv;
            c_lds[quad * 4 + 3][j] = e3 * inv;
        } else if (quad == 2) {
            c_lds[8][j] = e0 * inv;
            c_lds[9][j] = e1 * inv;
        }
    }
    __syncthreads();

    // ---- Cx[i][d] = sum_j c[i][j] * x[j][d]; thread owns column d = t.
    // x-reads: 64 lanes contiguous u16 = 128B, conflict-free; c-reads: LDS
    // broadcast (float2 over adjacent j). FIRST: c = 0.1 uniform.
    float cxa[10];
    if (FIRST) {
        float s = 0.f;
#pragma unroll 8
        for (int j = 0; j < 64; ++j) s += bf2f(xs[j * XP + t]);
        s *= 0.1f;
#pragma unroll
        for (int i = 0; i < 10; ++i) cxa[i] = s;
    } else {
#pragma unroll
        for (int i = 0; i < 10; ++i) cxa[i] = 0.f;
#pragma unroll 4
        for (int j = 0; j < 64; j += 2) {
            float x0 = bf2f(xs[j * XP + t]);
            float x1 = bf2f(xs[(j + 1) * XP + t]);
#pragma unroll
            for (int i = 0; i < 10; ++i) {
                float2 cc = *(const float2*)&c_lds[i][j];
                cxa[i] += cc.x * x0 + cc.y * x1;
            }
        }
    }
    float* pout = pcx + (size_t)blk * 10 * KP;   // blk = b*8+jo
#pragma unroll
    for (int i = 0; i < 10; ++i) pout[i * KP + t] = cxa[i];
}

// ---------------- combine: Cx -> po -> squash -> out; then Wo = W^T.out ----------------
// Round-4 verified version. Grid (b,i) = 1280 blocks x 256 thr.
// MODE 1: mid iteration (write wot). MODE 2: last (write dst, skip Wo).

template<int MODE>
__global__ __launch_bounds__(256)
void k_out(const float* __restrict__ src, const float* __restrict__ W,
           const ushort* __restrict__ wt, ushort* __restrict__ wot,
           float* __restrict__ dst) {
    __shared__ __align__(16) float cx[KP];
    __shared__ __align__(16) float red[4 * 64];
    __shared__ __align__(16) float outl[DC];
    const int blk = blockIdx.x;
    const int b = blk / 10, i = blk - b * 10;
    const int t = threadIdx.x, w = t >> 6, lane = t & 63;

    // phase 1: cx[d] = sum of 8 jb-partials for this (b,i)
    for (int d = t; d < KP; d += 256) {
        const float* pp = src + (size_t)b * 8 * 10 * KP + (size_t)i * KP + d;
        float v = 0.f;
#pragma unroll
        for (int jb = 0; jb < 8; ++jb) v += pp[(size_t)jb * 10 * KP];
        cx[d] = v;
    }
    __syncthreads();

    // phase 2: po[k] = sum_d cx[d]*wt[i*64+k][d]; d split over 4 waves (80 each)
    {
        const ushort* wr = wt + (size_t)(i * 64 + lane) * KP + w * 80;
        const float* cr = cx + w * 80;
        float pp = 0.f;
#pragma unroll
        for (int kk = 0; kk < 10; ++kk) {
            union { uint4 q; ushort u[8]; } wv;
            wv.q = *(const uint4*)(wr + kk * 8);
#pragma unroll
            for (int e = 0; e < 8; ++e) pp += bf2f(wv.u[e]) * cr[kk * 8 + e];
        }
        red[w * 64 + lane] = pp;
    }
    __syncthreads();
    if (w == 0) {
        float po = red[lane] + red[64 + lane] + red[128 + lane] + red[192 + lane];
        float sq = po * po;
#pragma unroll
        for (int m = 32; m >= 1; m >>= 1) sq += __shfl_xor(sq, m, 64);
        float ov = po * rsqrtf(sq + 1e-7f);
        if (MODE == 2) dst[(size_t)b * MM + i * 64 + lane] = ov;
        else           outl[lane] = ov;
    }
    if (MODE == 2) return;
    __syncthreads();

    // phase 3: Wo[d] = sum_k W[d][i*64+k]*outl[k]; write hi/lo bf16 split
    for (int d = t; d < KP; d += 256) {
        float s = 0.f;
        if (d < DD) {
            const float4* wr4 = (const float4*)(W + (size_t)d * MM + i * 64);
            const float4* ol4 = (const float4*)outl;
#pragma unroll
            for (int kk = 0; kk < 16; ++kk) {
                float4 a = wr4[kk];
                float4 o = ol4[kk];
                s += a.x * o.x + a.y * o.y + a.z * o.z + a.w * o.w;
            }
        }
        ushort hu = f2bf(s);
        wot[((size_t)(b * 2 + 0) * 16 + i) * KP + d] = hu;
        wot[((size_t)(b * 2 + 1) * 16 + i) * KP + d] = f2bf(s - bf2f(hu));
    }
}

// ---------------- launch: 12 dispatches (boundaries measured ~free, round 0) ----------------

extern "C" void kernel_launch(void* const* d_in, const int* in_sizes, int n_in,
                              void* d_out, int out_size, void* d_ws, size_t ws_size,
                              hipStream_t stream) {
    const float* x = (const float*)d_in[0];   // [128,512,300]
    const float* W = (const float*)d_in[1];   // [1,300,640]
    float* out = (float*)d_out;               // [128,10,64]

    char* ws = (char*)d_ws;
    size_t o = 0;
    ushort* xb  = (ushort*)(ws + o); o += (size_t)BQ * NJ * KP * 2;        // 41.9 MB
    ushort* wt  = (ushort*)(ws + o); o += (size_t)MM * KP * 2;             // 0.4 MB
    ushort* wot = (ushort*)(ws + o); o += (size_t)BQ * 2 * 16 * KP * 2;    // 2.6 MB
    float* pcx  = (float*)(ws + o);  o += (size_t)BQ * 8 * 10 * KP * 4;    // 13.1 MB

    k_cast_x<<<(BQ * NJ * 40) / 256, 256, 0, stream>>>(x, xb);
    k_cast_w<<<(MM * KP) / 256, 256, 0, stream>>>(W, wt);

    // iteration 0: uniform c -> Cx_0 = 0.1 * colsum(x); out_0; Wo(out_0)
    k_pass<1><<<BQ * 8, 320, 0, stream>>>(xb, wot, pcx);
    k_out<1><<<BQ * NC, 256, 0, stream>>>(pcx, W, wt, wot, nullptr);
    // iterations 1..4
    k_pass<0><<<BQ * 8, 320, 0, stream>>>(xb, wot, pcx);
    k_out<1><<<BQ * NC, 256, 0, stream>>>(pcx, W, wt, wot, nullptr);
    k_pass<0><<<BQ * 8, 320, 0, stream>>>(xb, wot, pcx);
    k_out<1><<<BQ * NC, 256, 0, stream>>>(pcx, W, wt, wot, nullptr);
    k_pass<0><<<BQ * 8, 320, 0, stream>>>(xb, wot, pcx);
    k_out<1><<<BQ * NC, 256, 0, stream>>>(pcx, W, wt, wot, nullptr);
    k_pass<0><<<BQ * 8, 320, 0, stream>>>(xb, wot, pcx);
    k_out<2><<<BQ * NC, 256, 0, stream>>>(pcx, W, wt, wot, out);
}